// Round 17
// baseline (537.960 us; speedup 1.0000x reference)
//
#include <hip/hip_runtime.h>
#include <hip/hip_bf16.h>

// BitNet 4-layer MLP forward, MI355X — round 17: B back to i8 staging.
// Ledger: staged bytes null (r7), co-residency null (r6/r10), VALU binding
// (r12/r13 calibrated ~0.44us per VALU/tile). So drop the 2-bit unpack
// entirely: B staged as plain i8 ternary (r6's verified path) on the r16
// diet structure. No rsum, simpler epilogue. L2/L3: 96KB dbuf, 1 blk/CU.

typedef __attribute__((ext_vector_type(4))) int i32x4_t;

#define GLDS16(g, l) __builtin_amdgcn_global_load_lds( \
    (const __attribute__((address_space(1))) unsigned int*)(g), \
    (__attribute__((address_space(3))) unsigned int*)(l), 16, 0, 0)

// ---------------- merged weight abs-mean: one pass over all 4 tensors -------
__global__ __launch_bounds__(256) void absmean4_part_k(
    const float* __restrict__ w1, const float* __restrict__ w2,
    const float* __restrict__ w3, const float* __restrict__ w4,
    double* __restrict__ part)
{
  const int b = blockIdx.x;
  const float* W; int n4, b0, nb;
  if (b < 128)       { W = w1; n4 = 1 << 20; b0 = 0;    nb = 128; }
  else if (b < 640)  { W = w2; n4 = 1 << 22; b0 = 128;  nb = 512; }
  else if (b < 1152) { W = w3; n4 = 1 << 22; b0 = 640;  nb = 512; }
  else               { W = w4; n4 = 1 << 20; b0 = 1152; nb = 128; }
  double s = 0.0;
  const int stride = nb * 256;
  for (int i = (b - b0) * 256 + threadIdx.x; i < n4; i += stride) {
    float4 v = ((const float4*)W)[i];
    s += (double)fabsf(v.x); s += (double)fabsf(v.y);
    s += (double)fabsf(v.z); s += (double)fabsf(v.w);
  }
  __shared__ double sd[256];
  sd[threadIdx.x] = s;
  __syncthreads();
  for (int st = 128; st > 0; st >>= 1) {
    if (threadIdx.x < st) sd[threadIdx.x] += sd[threadIdx.x + st];
    __syncthreads();
  }
  if (threadIdx.x == 0) part[b] = sd[0];
}

__global__ __launch_bounds__(256) void absmean4_fin_k(
    const double* __restrict__ part, float* __restrict__ wsc)
{
  __shared__ double sd[256];
  const int tid = threadIdx.x;
  const int seg[5] = {0, 128, 640, 1152, 1280};
  const double nel[4] = {4194304.0, 16777216.0, 16777216.0, 4194304.0};
  for (int si = 0; si < 4; ++si) {
    double s = 0.0;
    for (int i = seg[si] + tid; i < seg[si + 1]; i += 256) s += part[i];
    sd[tid] = s;
    __syncthreads();
    for (int st = 128; st > 0; st >>= 1) {
      if (tid < st) sd[tid] += sd[tid + st];
      __syncthreads();
    }
    if (tid == 0) {
      float mean = (float)(sd[0] / nel[si]);
      float scale = 1.f / fmaxf(mean, 1e-5f);
      wsc[si * 2]     = scale;
      wsc[si * 2 + 1] = 1.f / scale;
    }
    __syncthreads();
  }
}

// ------- merged weight ternary quantization to i8 {-1,0,1}, [N][K] ----------
// One thread packs 16 consecutive k of one output row -> uint4 store.
__global__ __launch_bounds__(256) void quant_w_i8_4_k(
    const float* __restrict__ w1, const float* __restrict__ w2,
    const float* __restrict__ w3, const float* __restrict__ w4,
    signed char* __restrict__ q1, signed char* __restrict__ q2,
    signed char* __restrict__ q3, signed char* __restrict__ q4,
    const float* __restrict__ wsc)
{
  int idx = blockIdx.x * 256 + threadIdx.x;
  const float* W; signed char* Wq; int Kd, widx;
  if (idx < 262144)        { W = w1; Wq = q1; Kd = 1024; widx = 0; }
  else if (idx < 1310720)  { idx -= 262144;  W = w2; Wq = q2; Kd = 4096; widx = 1; }
  else if (idx < 2359296)  { idx -= 1310720; W = w3; Wq = q3; Kd = 4096; widx = 2; }
  else                     { idx -= 2359296; W = w4; Wq = q4; Kd = 4096; widx = 3; }
  const float s = wsc[widx * 2];
  const int kg = idx & (Kd / 16 - 1);
  const int o  = idx / (Kd / 16);
  const float4* wr = (const float4*)(W + (size_t)o * Kd + kg * 16);
  unsigned int wd[4];
  #pragma unroll
  for (int j = 0; j < 4; ++j) {
    const float4 v = wr[j];
    const int qx = (int)fminf(fmaxf(rintf(v.x * s), -1.f), 1.f);
    const int qy = (int)fminf(fmaxf(rintf(v.y * s), -1.f), 1.f);
    const int qz = (int)fminf(fmaxf(rintf(v.z * s), -1.f), 1.f);
    const int qw = (int)fminf(fmaxf(rintf(v.w * s), -1.f), 1.f);
    wd[j] = (unsigned int)(qx & 255) | ((unsigned int)(qy & 255) << 8) |
            ((unsigned int)(qz & 255) << 16) | ((unsigned int)(qw & 255) << 24);
  }
  *(uint4*)(Wq + (size_t)o * Kd + kg * 16) = make_uint4(wd[0], wd[1], wd[2], wd[3]);
}

// -------- per-row activation quantization to i8 (fp32 / q15 input) ----------
template<int D, bool IN16>
__global__ __launch_bounds__(256) void act_quant_k(
    const void* __restrict__ Xv, unsigned int* __restrict__ Xq,
    float* __restrict__ inv_sa)
{
  constexpr int PT = D / 256;
  const int row = blockIdx.x, tid = threadIdx.x;
  float xv[PT];
  if constexpr (IN16) {
    const uint4* xr = (const uint4*)((const short*)Xv + (size_t)row * D);
    #pragma unroll
    for (int i = 0; i < PT / 8; ++i) {
      const uint4 u = xr[tid + 256 * i];
      const unsigned int w[4] = {u.x, u.y, u.z, u.w};
      #pragma unroll
      for (int j = 0; j < 4; ++j) {
        xv[i * 8 + 2 * j]     = (float)(short)(w[j] & 0xffffu) * (1.f / 32767.f);
        xv[i * 8 + 2 * j + 1] = (float)(short)(w[j] >> 16)     * (1.f / 32767.f);
      }
    }
  } else {
    const float4* xr = (const float4*)((const float*)Xv + (size_t)row * D);
    #pragma unroll
    for (int i = 0; i < PT / 4; ++i) {
      const float4 v = xr[tid + 256 * i];
      xv[i * 4] = v.x; xv[i * 4 + 1] = v.y;
      xv[i * 4 + 2] = v.z; xv[i * 4 + 3] = v.w;
    }
  }
  float m = 0.f;
  #pragma unroll
  for (int i = 0; i < PT; ++i) m = fmaxf(m, fabsf(xv[i]));
  #pragma unroll
  for (int off = 32; off >= 1; off >>= 1) m = fmaxf(m, __shfl_xor(m, off));
  __shared__ float wm[4];
  if ((tid & 63) == 0) wm[tid >> 6] = m;
  __syncthreads();
  m = fmaxf(fmaxf(wm[0], wm[1]), fmaxf(wm[2], wm[3]));
  const float s = 127.f / fmaxf(m, 1e-5f);
  if (tid == 0) inv_sa[row] = 1.f / s;
  unsigned int* oq = Xq + (size_t)row * (D / 4);
  #pragma unroll
  for (int di = 0; di < PT / 4; ++di) {
    int q[4];
    #pragma unroll
    for (int e = 0; e < 4; ++e)
      q[e] = (int)fminf(fmaxf(rintf(xv[di * 4 + e] * s), -128.f), 127.f);
    const unsigned int pk =
        (unsigned int)(q[0] & 255) | ((unsigned int)(q[1] & 255) << 8) |
        ((unsigned int)(q[2] & 255) << 16) | ((unsigned int)(q[3] & 255) << 24);
    int gd;
    if constexpr (IN16) gd = 2 * (tid + 256 * (di / 2)) + (di & 1);
    else                gd = tid + 256 * di;
    oq[gd] = pk;
  }
}

// ---- BMx128 dbuf i8-A / i8-B GEMM (BM in {256,128}) ------------------------
// 8 waves: (BM/64) M-waves x NW N-waves; per-wave 64 x (128/NW) cols.
// A: BM*128 i8 + B: 128*128 i8 = BUFSZ; 3-bit XOR slot swizzle both (r6/r7-
// verified conflict-free). Stage: NAG A-GLDS + 2 B-GLDS per thread.
// TANH layers store q15 int16 h; final stores fp32.
template<int BM, int K, int N, bool TANH>
__global__ __launch_bounds__(512, 4) void gemm2p(
    const signed char* __restrict__ A, const signed char* __restrict__ Wq,
    const float* __restrict__ inv_sa, const float* __restrict__ wsc, int widx,
    const float* __restrict__ bias, void* __restrict__ outv)
{
  constexpr int MW   = BM / 64;
  constexpr int NW   = 8 / MW;
  constexpr int LNW  = (NW == 2) ? 1 : 2;
  constexpr int PC   = 128 / NW;
  constexpr int NPL  = PC / 16;
  constexpr int NAG  = BM / 64;
  constexpr int BOFF = BM * 128;               // B region start in buffer
  constexpr int BUFSZ = BM * 128 + 16384;
  __shared__ __align__(16) signed char lds[2 * BUFSZ];
  constexpr int NT = K / 128;
  constexpr int VC = NAG + 2;                  // GLDS per stage per thread
  const int tid = threadIdx.x;
  const int wv = tid >> 6, ln = tid & 63;
  const int wr = wv >> LNW, wc = wv & (NW - 1);
  const int g = ln >> 4, rl = ln & 15;
  const int colswz = (rl & 7) << 4;

  // XCD-aware block swizzle (nwg % 8 == 0 for all grids used)
  const int nwg = gridDim.x * gridDim.y;
  int lbid = blockIdx.y * gridDim.x + blockIdx.x;
  lbid = (lbid & 7) * (nwg >> 3) + (lbid >> 3);
  const int bn = lbid % gridDim.x, bm = lbid / gridDim.x;

  const signed char* Abase = A + (size_t)bm * BM * K;
  const signed char* Wqb = Wq + (size_t)bn * 128 * K;

  // ---- hoisted per-lane constants ----
  const int myAoff = wr * 8192;
  const int aoff0 = myAoff + rl * 128 + ((g * 16) ^ colswz);
  const int aoff1 = myAoff + rl * 128 + ((64 + g * 16) ^ colswz);
  const int myBoff = BOFF + wc * (PC * 128);
  const int boff0 = myBoff + rl * 128 + ((g * 16) ^ colswz);
  const int boff1 = myBoff + rl * 128 + ((64 + g * 16) ^ colswz);
  int srcA[NAG], dstA[NAG];
  #pragma unroll
  for (int i = 0; i < NAG; ++i) {
    const int c = tid + 512 * i;
    srcA[i] = (c >> 3) * K + ((c ^ (c >> 3)) & 7) * 16;
    dstA[i] = c * 16;
  }
  int srcB[2], dstB[2];
  #pragma unroll
  for (int i = 0; i < 2; ++i) {
    const int c = tid + 512 * i;
    srcB[i] = (c >> 3) * K + ((c ^ (c >> 3)) & 7) * 16;
    dstB[i] = BOFF + c * 16;
  }

  auto stage = [&](int tt) {
    if (tt >= NT) return;
    signed char* d = lds + (tt & 1) * BUFSZ;
    const signed char* sA = Abase + tt * 128;
    const signed char* sB = Wqb + tt * 128;
    #pragma unroll
    for (int i = 0; i < NAG; ++i) GLDS16(sA + srcA[i], d + dstA[i]);
    #pragma unroll
    for (int i = 0; i < 2; ++i) GLDS16(sB + srcB[i], d + dstB[i]);
  };

  i32x4_t acc[4][NPL];
  #pragma unroll
  for (int m = 0; m < 4; ++m)
    #pragma unroll
    for (int n = 0; n < NPL; ++n) acc[m][n] = (i32x4_t){0, 0, 0, 0};

  // prologue
  stage(0); stage(1);
  if (NT > 1) {
    if constexpr (VC == 6) asm volatile("s_waitcnt vmcnt(6)" ::: "memory");
    else                   asm volatile("s_waitcnt vmcnt(4)" ::: "memory");
  } else {
    asm volatile("s_waitcnt vmcnt(0)" ::: "memory");
  }
  __builtin_amdgcn_s_barrier();

  for (int t = 0; t < NT; ++t) {
    const signed char* bufb = lds + (t & 1) * BUFSZ;
    const signed char* pa0 = bufb + aoff0;
    const signed char* pa1 = bufb + aoff1;
    const signed char* pb0 = bufb + boff0;
    const signed char* pb1 = bufb + boff1;

    i32x4_t bfr[2][NPL];
    #pragma unroll
    for (int np = 0; np < NPL; ++np) {
      bfr[0][np] = *(const i32x4_t*)(pb0 + np * 2048);
      bfr[1][np] = *(const i32x4_t*)(pb1 + np * 2048);
    }

    __builtin_amdgcn_s_setprio(1);
    #pragma unroll
    for (int ks = 0; ks < 2; ++ks) {
      const signed char* pa = ks ? pa1 : pa0;
      #pragma unroll
      for (int m = 0; m < 4; ++m) {
        const i32x4_t af = *(const i32x4_t*)(pa + m * 2048);
        #pragma unroll
        for (int np = 0; np < NPL; ++np)
          acc[m][np] = __builtin_amdgcn_mfma_i32_16x16x64_i8(
              af, bfr[ks][np], acc[m][np], 0, 0, 0);
      }
    }
    __builtin_amdgcn_s_setprio(0);

    asm volatile("s_waitcnt lgkmcnt(0)" ::: "memory");
    __builtin_amdgcn_s_barrier();            // all waves done reading buf[cur]
    stage(t + 2);                            // refill buf[cur] with tile t+2
    if (t + 2 < NT) {
      if constexpr (VC == 6) asm volatile("s_waitcnt vmcnt(6)" ::: "memory");
      else                   asm volatile("s_waitcnt vmcnt(4)" ::: "memory");
    } else {
      asm volatile("s_waitcnt vmcnt(0)" ::: "memory");
    }
    __builtin_amdgcn_s_barrier();            // tile t+1 confirmed resident
  }

  // -------- epilogue: scale, bias, fast tanh, store -------------------------
  const float invw = wsc[widx * 2 + 1];
  const int row0 = bm * BM + wr * 64;
  const int col0 = bn * 128 + wc * PC;
  #pragma unroll
  for (int m = 0; m < 4; ++m) {
    #pragma unroll
    for (int r = 0; r < 4; ++r) {
      const int gb = row0 + m * 16 + g * 4 + r;
      const float fa = inv_sa[gb] * invw;
      #pragma unroll
      for (int np = 0; np < NPL; ++np) {
        const int go = col0 + np * 16 + rl;
        const float v = (float)acc[m][np][r] * fa + bias[go];
        if constexpr (TANH) {
          const float e2 = __expf(2.f * v);
          const float th = 1.f - 2.f * __builtin_amdgcn_rcpf(e2 + 1.f);
          const float q = fminf(fmaxf(rintf(th * 32767.f), -32767.f), 32767.f);
          ((short*)outv)[(size_t)gb * N + go] = (short)q;
        } else {
          ((float*)outv)[(size_t)gb * N + go] = v;
        }
      }
    }
  }
}

// ---------------- driver ----------------------------------------------------
extern "C" void kernel_launch(void* const* d_in, const int* in_sizes, int n_in,
                              void* d_out, int out_size, void* d_ws, size_t ws_size,
                              hipStream_t stream)
{
  const float* x  = (const float*)d_in[0];
  const float* w1 = (const float*)d_in[1]; const float* b1 = (const float*)d_in[2];
  const float* w2 = (const float*)d_in[3]; const float* b2 = (const float*)d_in[4];
  const float* w3 = (const float*)d_in[5]; const float* b3 = (const float*)d_in[6];
  const float* w4 = (const float*)d_in[7]; const float* b4 = (const float*)d_in[8];
  float* out = (float*)d_out;

  constexpr int B = 8192, DIN = 1024, H = 4096, DOUT = 1024;
  char* ws = (char*)d_ws;
  size_t off = 0;
  short*        hbuf = (short*)(ws + off);        off += (size_t)B * H * 2;   // 64 MB
  signed char*  xq   = (signed char*)(ws + off);  off += (size_t)B * H;
  signed char*  wq1  = (signed char*)(ws + off);  off += (size_t)H * DIN;
  signed char*  wq2  = (signed char*)(ws + off);  off += (size_t)H * H;
  signed char*  wq3  = (signed char*)(ws + off);  off += (size_t)H * H;
  signed char*  wq4  = (signed char*)(ws + off);  off += (size_t)DOUT * H;
  float*        inv_sa = (float*)(ws + off);      off += (size_t)B * 4;
  double*       part = (double*)(ws + off);       off += 1280 * 8;
  float*        wsc  = (float*)(ws + off);        off += 64;

  // weight prep: 3 launches for all four tensors
  absmean4_part_k<<<1280, 256, 0, stream>>>(w1, w2, w3, w4, part);
  absmean4_fin_k<<<1, 256, 0, stream>>>(part, wsc);
  quant_w_i8_4_k<<<10240, 256, 0, stream>>>(w1, w2, w3, w4,
                                            wq1, wq2, wq3, wq4, wsc);

  // layer 1: K=DIN=1024, N=H (fp32 input path)
  act_quant_k<DIN, false><<<B, 256, 0, stream>>>(x, (unsigned int*)xq, inv_sa);
  gemm2p<256, DIN, H, true><<<dim3(H / 128, B / 256), 512, 0, stream>>>(
      xq, wq1, inv_sa, wsc, 0, b1, hbuf);

  // layer 2: K=H, N=H (q15 h path)
  act_quant_k<H, true><<<B, 256, 0, stream>>>(hbuf, (unsigned int*)xq, inv_sa);
  gemm2p<256, H, H, true><<<dim3(H / 128, B / 256), 512, 0, stream>>>(
      xq, wq2, inv_sa, wsc, 1, b2, hbuf);

  // layer 3: K=H, N=H
  act_quant_k<H, true><<<B, 256, 0, stream>>>(hbuf, (unsigned int*)xq, inv_sa);
  gemm2p<256, H, H, true><<<dim3(H / 128, B / 256), 512, 0, stream>>>(
      xq, wq3, inv_sa, wsc, 2, b3, hbuf);

  // layer 4: K=H, N=DOUT, no tanh — BM=128 (64KB dbuf, 2 blocks/CU), fp32 out
  act_quant_k<H, true><<<B, 256, 0, stream>>>(hbuf, (unsigned int*)xq, inv_sa);
  gemm2p<128, H, DOUT, false><<<dim3(DOUT / 128, B / 128), 512, 0, stream>>>(
      xq, wq4, inv_sa, wsc, 3, b4, out);
}

// Round 18
// 448.152 us; speedup vs baseline: 1.2004x; 1.2004x over previous
//
#include <hip/hip_runtime.h>
#include <hip/hip_bf16.h>

// BitNet 4-layer MLP forward, MI355X — round 18: r16 base + 2Mx4N wave grid.
// r17 (i8-B) regressed: packed-B's fetch compression is load-bearing; revert.
// r16's wave tile 64x64 spends 64 unpack-VALU vs 32 MFMA per tile. 2Mx4N
// (wave tile 128x32) halves B frags -> 32 unpack, A reads 16 b128 (free,
// immediate-folded). Same LDS layout/staging/swizzles as r16.

typedef __attribute__((ext_vector_type(4))) int i32x4_t;

#define GLDS16(g, l) __builtin_amdgcn_global_load_lds( \
    (const __attribute__((address_space(1))) unsigned int*)(g), \
    (__attribute__((address_space(3))) unsigned int*)(l), 16, 0, 0)

// ---------------- merged weight abs-mean: one pass over all 4 tensors -------
__global__ __launch_bounds__(256) void absmean4_part_k(
    const float* __restrict__ w1, const float* __restrict__ w2,
    const float* __restrict__ w3, const float* __restrict__ w4,
    double* __restrict__ part)
{
  const int b = blockIdx.x;
  const float* W; int n4, b0, nb;
  if (b < 128)       { W = w1; n4 = 1 << 20; b0 = 0;    nb = 128; }
  else if (b < 640)  { W = w2; n4 = 1 << 22; b0 = 128;  nb = 512; }
  else if (b < 1152) { W = w3; n4 = 1 << 22; b0 = 640;  nb = 512; }
  else               { W = w4; n4 = 1 << 20; b0 = 1152; nb = 128; }
  double s = 0.0;
  const int stride = nb * 256;
  for (int i = (b - b0) * 256 + threadIdx.x; i < n4; i += stride) {
    float4 v = ((const float4*)W)[i];
    s += (double)fabsf(v.x); s += (double)fabsf(v.y);
    s += (double)fabsf(v.z); s += (double)fabsf(v.w);
  }
  __shared__ double sd[256];
  sd[threadIdx.x] = s;
  __syncthreads();
  for (int st = 128; st > 0; st >>= 1) {
    if (threadIdx.x < st) sd[threadIdx.x] += sd[threadIdx.x + st];
    __syncthreads();
  }
  if (threadIdx.x == 0) part[b] = sd[0];
}

__global__ __launch_bounds__(256) void absmean4_fin_k(
    const double* __restrict__ part, float* __restrict__ wsc)
{
  __shared__ double sd[256];
  const int tid = threadIdx.x;
  const int seg[5] = {0, 128, 640, 1152, 1280};
  const double nel[4] = {4194304.0, 16777216.0, 16777216.0, 4194304.0};
  for (int si = 0; si < 4; ++si) {
    double s = 0.0;
    for (int i = seg[si] + tid; i < seg[si + 1]; i += 256) s += part[i];
    sd[tid] = s;
    __syncthreads();
    for (int st = 128; st > 0; st >>= 1) {
      if (tid < st) sd[tid] += sd[tid + st];
      __syncthreads();
    }
    if (tid == 0) {
      float mean = (float)(sd[0] / nel[si]);
      float scale = 1.f / fmaxf(mean, 1e-5f);
      wsc[si * 2]     = scale;
      wsc[si * 2 + 1] = 1.f / scale;
    }
    __syncthreads();
  }
}

// ------- merged weight pack (biased {0,1,2} 2-bit), float4-vectorized -------
__global__ __launch_bounds__(256) void quant_w_pack4_k(
    const float* __restrict__ w1, const float* __restrict__ w2,
    const float* __restrict__ w3, const float* __restrict__ w4,
    unsigned int* __restrict__ wp1, unsigned int* __restrict__ wp2,
    unsigned int* __restrict__ wp3, unsigned int* __restrict__ wp4,
    const float* __restrict__ wsc)
{
  int idx = blockIdx.x * 256 + threadIdx.x;
  const float* W; unsigned int* Wp; int Kd, Nd, widx;
  if (idx < 262144)        { W = w1; Wp = wp1; Kd = 1024; Nd = 4096; widx = 0; }
  else if (idx < 1310720)  { idx -= 262144;  W = w2; Wp = wp2; Kd = 4096; Nd = 4096; widx = 1; }
  else if (idx < 2359296)  { idx -= 1310720; W = w3; Wp = wp3; Kd = 4096; Nd = 4096; widx = 2; }
  else                     { idx -= 2359296; W = w4; Wp = wp4; Kd = 4096; Nd = 1024; widx = 3; }
  const float s = wsc[widx * 2];
  const int kc = idx & (Kd / 16 - 1);
  const int o  = idx / (Kd / 16);
  const float4* wr = (const float4*)(W + (size_t)o * Kd + kc * 16);
  unsigned int u = 0;
  #pragma unroll
  for (int q4 = 0; q4 < 4; ++q4) {
    const float4 v = wr[q4];
    int q;
    q = (int)fminf(fmaxf(rintf(v.x * s), -1.f), 1.f); u |= (unsigned int)(q + 1) << (2 * q4);
    q = (int)fminf(fmaxf(rintf(v.y * s), -1.f), 1.f); u |= (unsigned int)(q + 1) << (8 + 2 * q4);
    q = (int)fminf(fmaxf(rintf(v.z * s), -1.f), 1.f); u |= (unsigned int)(q + 1) << (16 + 2 * q4);
    q = (int)fminf(fmaxf(rintf(v.w * s), -1.f), 1.f); u |= (unsigned int)(q + 1) << (24 + 2 * q4);
  }
  Wp[(size_t)kc * Nd + o] = u;
}

// -------- per-row activation quantization to i8 + row-sum (fp32/q15 in) -----
template<int D, bool IN16>
__global__ __launch_bounds__(256) void act_quant_k(
    const void* __restrict__ Xv, unsigned int* __restrict__ Xq,
    float* __restrict__ inv_sa, int* __restrict__ rsum)
{
  constexpr int PT = D / 256;
  const int row = blockIdx.x, tid = threadIdx.x;
  float xv[PT];
  if constexpr (IN16) {
    const uint4* xr = (const uint4*)((const short*)Xv + (size_t)row * D);
    #pragma unroll
    for (int i = 0; i < PT / 8; ++i) {
      const uint4 u = xr[tid + 256 * i];
      const unsigned int w[4] = {u.x, u.y, u.z, u.w};
      #pragma unroll
      for (int j = 0; j < 4; ++j) {
        xv[i * 8 + 2 * j]     = (float)(short)(w[j] & 0xffffu) * (1.f / 32767.f);
        xv[i * 8 + 2 * j + 1] = (float)(short)(w[j] >> 16)     * (1.f / 32767.f);
      }
    }
  } else {
    const float4* xr = (const float4*)((const float*)Xv + (size_t)row * D);
    #pragma unroll
    for (int i = 0; i < PT / 4; ++i) {
      const float4 v = xr[tid + 256 * i];
      xv[i * 4] = v.x; xv[i * 4 + 1] = v.y;
      xv[i * 4 + 2] = v.z; xv[i * 4 + 3] = v.w;
    }
  }
  float m = 0.f;
  #pragma unroll
  for (int i = 0; i < PT; ++i) m = fmaxf(m, fabsf(xv[i]));
  #pragma unroll
  for (int off = 32; off >= 1; off >>= 1) m = fmaxf(m, __shfl_xor(m, off));
  __shared__ float wm[4];
  if ((tid & 63) == 0) wm[tid >> 6] = m;
  __syncthreads();
  m = fmaxf(fmaxf(wm[0], wm[1]), fmaxf(wm[2], wm[3]));
  const float s = 127.f / fmaxf(m, 1e-5f);
  if (tid == 0) inv_sa[row] = 1.f / s;
  unsigned int* oq = Xq + (size_t)row * (D / 4);
  int isum = 0;
  #pragma unroll
  for (int di = 0; di < PT / 4; ++di) {
    int q[4];
    #pragma unroll
    for (int e = 0; e < 4; ++e) {
      q[e] = (int)fminf(fmaxf(rintf(xv[di * 4 + e] * s), -128.f), 127.f);
      isum += q[e];
    }
    const unsigned int pk =
        (unsigned int)(q[0] & 255) | ((unsigned int)(q[1] & 255) << 8) |
        ((unsigned int)(q[2] & 255) << 16) | ((unsigned int)(q[3] & 255) << 24);
    int gd;
    if constexpr (IN16) gd = 2 * (tid + 256 * (di / 2)) + (di & 1);
    else                gd = tid + 256 * di;
    oq[gd] = pk;
  }
  #pragma unroll
  for (int off = 32; off >= 1; off >>= 1) isum += __shfl_xor(isum, off);
  __shared__ int wsum[4];
  if ((tid & 63) == 0) wsum[tid >> 6] = isum;
  __syncthreads();
  if (tid == 0) rsum[row] = wsum[0] + wsum[1] + wsum[2] + wsum[3];
}

// ---- BMx128 dbuf i8-A / 2-bit-biased-B GEMM, 2Mx4N wave grid ---------------
// 8 waves: 2 M-waves x 4 N-waves; per-wave (BM/2) rows x 32 cols.
// MR = BM/32 m-frags, NPL = 2. B unpack halved vs r16 (32 VALU/tile).
// LDS layout, staging, swizzles identical to r16 (verified, 0 conflicts).
template<int BM, int K, int N, bool TANH>
__global__ __launch_bounds__(512, 4) void gemm2p(
    const signed char* __restrict__ A, const unsigned int* __restrict__ Wp,
    const float* __restrict__ inv_sa, const int* __restrict__ rsum,
    const float* __restrict__ wsc, int widx,
    const float* __restrict__ bias, void* __restrict__ outv)
{
  constexpr int MR   = BM / 32;          // m-frags per wave
  constexpr int NPL  = 2;                // np-frags per wave
  constexpr int NAG  = BM / 64;          // per-thread A-stage GLDS
  constexpr int BOFF = BM * 128;
  constexpr int BUFSZ = BM * 128 + 4096;
  __shared__ __align__(16) signed char lds[2 * BUFSZ];
  constexpr int NT = K / 128;
  const int tid = threadIdx.x;
  const int wv = tid >> 6, ln = tid & 63;
  const int wr = wv >> 2, wc = wv & 3;   // 2 x 4 wave grid
  const int g = ln >> 4, rl = ln & 15;
  const int colswz = (rl & 7) << 4;

  // XCD-aware block swizzle (nwg % 8 == 0 for all grids used)
  const int nwg = gridDim.x * gridDim.y;
  int lbid = blockIdx.y * gridDim.x + blockIdx.x;
  lbid = (lbid & 7) * (nwg >> 3) + (lbid >> 3);
  const int bn = lbid % gridDim.x, bm = lbid / gridDim.x;

  const signed char* Abase = A + (size_t)bm * BM * K;
  const signed char* Wpb = (const signed char*)(Wp + (size_t)bn * 128);

  // ---- hoisted per-lane constants ----
  const int myAoff = wr * (BM * 64);     // wr*(BM/2 rows)*128B
  const int bcol = wc * 32;              // dword cols
  const int aoff0 = myAoff + rl * 128 + ((g * 16) ^ colswz);
  const int aoff1 = myAoff + rl * 128 + ((64 + g * 16) ^ colswz);
  const int bswz = (g & 1) << 6;
  const int boffB = BOFF + g * 512 + 4 * (bcol + rl);
  int be[NPL];
  #pragma unroll
  for (int np = 0; np < NPL; ++np) be[np] = boffB + ((np * 64) ^ bswz);
  int srcA[NAG], dstA[NAG];
  #pragma unroll
  for (int i = 0; i < NAG; ++i) {
    const int c = tid + 512 * i;
    srcA[i] = (c >> 3) * K + ((c ^ (c >> 3)) & 7) * 16;
    dstA[i] = c * 16;
  }
  const int kcs = tid >> 5, js = tid & 31;
  const size_t srcB = (size_t)kcs * N * 4 + 4 * ((4 * js) ^ ((kcs & 1) << 4));
  const int dstB = BOFF + kcs * 512 + js * 16;

  auto stage = [&](int tt) {
    if (tt >= NT) return;
    signed char* dA = lds + (tt & 1) * BUFSZ;
    const signed char* sA = Abase + tt * 128;
    #pragma unroll
    for (int i = 0; i < NAG; ++i) GLDS16(sA + srcA[i], dA + dstA[i]);
    if (wv < 4)
      GLDS16(Wpb + (size_t)tt * (N * 32) + srcB, dA + dstB);
  };

  i32x4_t acc[MR][NPL];
  #pragma unroll
  for (int m = 0; m < MR; ++m)
    #pragma unroll
    for (int n = 0; n < NPL; ++n) acc[m][n] = (i32x4_t){0, 0, 0, 0};

  // prologue
  stage(0); stage(1);
  if constexpr (BM == 256) asm volatile("s_waitcnt vmcnt(4)" ::: "memory");
  else                     asm volatile("s_waitcnt vmcnt(2)" ::: "memory");
  __builtin_amdgcn_s_barrier();

  for (int t = 0; t < NT; ++t) {
    const signed char* bufb = lds + (t & 1) * BUFSZ;
    const signed char* pa0 = bufb + aoff0;
    const signed char* pa1 = bufb + aoff1;

    unsigned int bp[2][NPL];
    #pragma unroll
    for (int ks = 0; ks < 2; ++ks)
      #pragma unroll
      for (int np = 0; np < NPL; ++np)
        bp[ks][np] = *(const unsigned int*)(bufb + be[np] + ks * 2048);

    __builtin_amdgcn_s_setprio(1);
    #pragma unroll
    for (int ks = 0; ks < 2; ++ks) {
      i32x4_t bu[NPL];
      #pragma unroll
      for (int np = 0; np < NPL; ++np)
        #pragma unroll
        for (int j = 0; j < 4; ++j)
          bu[np][j] = (int)((bp[ks][np] >> (2 * j)) & 0x03030303u);
      const signed char* pa = ks ? pa1 : pa0;
      #pragma unroll
      for (int m = 0; m < MR; ++m) {
        const i32x4_t af = *(const i32x4_t*)(pa + m * 2048);
        #pragma unroll
        for (int np = 0; np < NPL; ++np)
          acc[m][np] = __builtin_amdgcn_mfma_i32_16x16x64_i8(
              af, bu[np], acc[m][np], 0, 0, 0);
      }
    }
    __builtin_amdgcn_s_setprio(0);

    asm volatile("s_waitcnt lgkmcnt(0)" ::: "memory");
    __builtin_amdgcn_s_barrier();
    stage(t + 2);
    if (t + 2 < NT) {
      if constexpr (BM == 256) asm volatile("s_waitcnt vmcnt(4)" ::: "memory");
      else                     asm volatile("s_waitcnt vmcnt(2)" ::: "memory");
    } else {
      asm volatile("s_waitcnt vmcnt(0)" ::: "memory");
    }
    __builtin_amdgcn_s_barrier();
  }

  // -------- epilogue: undo weight bias, scale, bias, fast tanh, store -------
  const float invw = wsc[widx * 2 + 1];
  const int row0 = bm * BM + wr * (BM / 2);
  const int col0 = bn * 128 + wc * 32;
  #pragma unroll
  for (int m = 0; m < MR; ++m) {
    #pragma unroll
    for (int r = 0; r < 4; ++r) {
      const int gb = row0 + m * 16 + g * 4 + r;
      const float fa = inv_sa[gb] * invw;
      const int sr = rsum[gb];
      #pragma unroll
      for (int np = 0; np < NPL; ++np) {
        const int go = col0 + np * 16 + rl;
        const float v = (float)(acc[m][np][r] - sr) * fa + bias[go];
        if constexpr (TANH) {
          const float e2 = __expf(2.f * v);
          const float th = 1.f - 2.f * __builtin_amdgcn_rcpf(e2 + 1.f);
          const float q = fminf(fmaxf(rintf(th * 32767.f), -32767.f), 32767.f);
          ((short*)outv)[(size_t)gb * N + go] = (short)q;
        } else {
          ((float*)outv)[(size_t)gb * N + go] = v;
        }
      }
    }
  }
}

// ---------------- driver ----------------------------------------------------
extern "C" void kernel_launch(void* const* d_in, const int* in_sizes, int n_in,
                              void* d_out, int out_size, void* d_ws, size_t ws_size,
                              hipStream_t stream)
{
  const float* x  = (const float*)d_in[0];
  const float* w1 = (const float*)d_in[1]; const float* b1 = (const float*)d_in[2];
  const float* w2 = (const float*)d_in[3]; const float* b2 = (const float*)d_in[4];
  const float* w3 = (const float*)d_in[5]; const float* b3 = (const float*)d_in[6];
  const float* w4 = (const float*)d_in[7]; const float* b4 = (const float*)d_in[8];
  float* out = (float*)d_out;

  constexpr int B = 8192, DIN = 1024, H = 4096, DOUT = 1024;
  char* ws = (char*)d_ws;
  size_t off = 0;
  short*        hbuf = (short*)(ws + off);        off += (size_t)B * H * 2;
  signed char*  xq   = (signed char*)(ws + off);  off += (size_t)B * H;
  unsigned int* wp1  = (unsigned int*)(ws + off); off += (size_t)(DIN / 16) * H * 4;
  unsigned int* wp2  = (unsigned int*)(ws + off); off += (size_t)(H / 16) * H * 4;
  unsigned int* wp3  = (unsigned int*)(ws + off); off += (size_t)(H / 16) * H * 4;
  unsigned int* wp4  = (unsigned int*)(ws + off); off += (size_t)(H / 16) * DOUT * 4;
  float*        inv_sa = (float*)(ws + off);      off += (size_t)B * 4;
  int*          rsum = (int*)(ws + off);          off += (size_t)B * 4;
  double*       part = (double*)(ws + off);       off += 1280 * 8;
  float*        wsc  = (float*)(ws + off);        off += 64;

  // weight prep: 3 launches for all four tensors
  absmean4_part_k<<<1280, 256, 0, stream>>>(w1, w2, w3, w4, part);
  absmean4_fin_k<<<1, 256, 0, stream>>>(part, wsc);
  quant_w_pack4_k<<<10240, 256, 0, stream>>>(w1, w2, w3, w4,
                                             wp1, wp2, wp3, wp4, wsc);

  // layer 1: K=DIN=1024, N=H (fp32 input path)
  act_quant_k<DIN, false><<<B, 256, 0, stream>>>(x, (unsigned int*)xq, inv_sa, rsum);
  gemm2p<256, DIN, H, true><<<dim3(H / 128, B / 256), 512, 0, stream>>>(
      xq, wp1, inv_sa, rsum, wsc, 0, b1, hbuf);

  // layer 2: K=H, N=H (q15 h path)
  act_quant_k<H, true><<<B, 256, 0, stream>>>(hbuf, (unsigned int*)xq, inv_sa, rsum);
  gemm2p<256, H, H, true><<<dim3(H / 128, B / 256), 512, 0, stream>>>(
      xq, wp2, inv_sa, rsum, wsc, 1, b2, hbuf);

  // layer 3: K=H, N=H
  act_quant_k<H, true><<<B, 256, 0, stream>>>(hbuf, (unsigned int*)xq, inv_sa, rsum);
  gemm2p<256, H, H, true><<<dim3(H / 128, B / 256), 512, 0, stream>>>(
      xq, wp3, inv_sa, rsum, wsc, 2, b3, hbuf);

  // layer 4: K=H, N=DOUT, no tanh — BM=128, fp32 out
  act_quant_k<H, true><<<B, 256, 0, stream>>>(hbuf, (unsigned int*)xq, inv_sa, rsum);
  gemm2p<128, H, DOUT, false><<<dim3(DOUT / 128, B / 128), 512, 0, stream>>>(
      xq, wp4, inv_sa, rsum, wsc, 3, b4, out);
}